// Round 7
// baseline (249.436 us; speedup 1.0000x reference)
//
#include <hip/hip_runtime.h>

// Correlation layer (FlowNet-style), max_displacement=4.
// in1,in2: [8,256,128,128] fp32 -> out: [8,81,128,128] fp32
// out[b, dy*9+dx, y, x] = sum_c in1[b,c,y,x] * in2[b,c,y+dy-4,x+dx-4] (0 if OOB)
//
// Round-7: MFMA formulation. Banded QK^T with v_mfma_f32_16x16x16_f16:
//   block = (b, y, x-half of 64 px), 9 waves, wave = dy.
//   Per wave: 4 m-windows x 2 band tiles (in2 stored at -4 px phase so both
//   B-windows are 16-aligned). 144/512 MFMA slots useful (28%) but the MFMA
//   pipe is nearly free vs the half-rate v_dot2 path (which had a ~40us floor).
//   LDS: k-major f16 [px][KS=20] tiles; frag read = 1 conflict-free ds_read_b64
//   matching the mfma lane layout (m=l&15, k=4*(l>>4)+j). Staging transposes
//   during the f32->f16 pack (4 strided b32 writes, 2-way = free).
//   acc 32 VGPR; launch_bounds(576,8) forces VGPR<=64 -> 3 blocks = 27 waves/CU.

constexpr int Bn = 8, Cn = 256, Hn = 128, Wn = 128, HW = Hn * Wn;
constexpr int ND = 9;
constexpr int KC  = 16;               // channels per k-chunk
constexpr int NCH = Cn / KC;          // 16 chunks
constexpr int NT  = 576;              // 9 waves, wave = dy
constexpr int KS  = 20;               // LDS k-stride (16 k + 4 pad), f16 elems
constexpr int IN1E = 0;               // in1 region base (64 px)
constexpr int IN2E = 64 * KS;         // 1280: in2 region (9 rows x 80 px)
constexpr int ROWE = 80 * KS;         // 1600 elems per in2 row
constexpr int TOTE = IN2E + 9 * ROWE; // 15680 f16 = 31.4 KB
constexpr int NT1 = 128;              // in1 staging tasks (8 kp x 16 quads)
constexpr int NT2 = 9 * 8 * 20;       // 1440 in2 tasks (9 ri x 8 kp x 20 quads)
constexpr int NTASK = NT1 + NT2;      // 1568

typedef __fp16 half4 __attribute__((ext_vector_type(4)));
typedef float  f32x4 __attribute__((ext_vector_type(4)));
typedef __fp16 h2v   __attribute__((ext_vector_type(2)));

static __device__ __forceinline__ unsigned packh2(float a, float b) {
  h2v h = __builtin_amdgcn_cvt_pkrtz(a, b);   // a->low, b->high
  return __builtin_bit_cast(unsigned, h);
}

static __device__ __forceinline__ f32x4 mfma16(half4 a, half4 b, f32x4 c) {
#if __has_builtin(__builtin_amdgcn_mfma_f32_16x16x16f16)
  return __builtin_amdgcn_mfma_f32_16x16x16f16(a, b, c, 0, 0, 0);
#else
  f32x4 d;
  asm volatile("v_mfma_f32_16x16x16_f16 %0, %1, %2, %3"
               : "=v"(d) : "v"(a), "v"(b), "v"(c));
  return d;
#endif
}

__global__ __launch_bounds__(NT, 8) void corr_kernel(
    const float* __restrict__ in1, const float* __restrict__ in2,
    float* __restrict__ out)
{
  __shared__ __align__(16) __fp16 sm[TOTE];

  // XCD swizzle: 2048 blocks, bijective (2048 % 8 == 0). Each XCD gets one
  // batch; within an XCD consecutive blocks walk (xh, y) -> in2 rows L2-hot.
  int bid = blockIdx.x;
  bid = (bid & 7) * 256 + (bid >> 3);
  const int b  = bid >> 8;
  const int y  = (bid >> 1) & 127;
  const int xh = bid & 1;
  const int X0 = xh << 6;              // 0 or 64
  const int XP0 = X0 - 4;              // x' origin of px-local (16*S0 - 4)

  const int tid = threadIdx.x;
  const int dy  = tid >> 6;            // wave id = dy
  const int l   = tid & 63;
  const int n   = l & 15;              // mfma n / m-col index
  const int g   = l >> 4;              // mfma k-group / m-row group

  const size_t gbase = (size_t)b * Cn * HW;

  // ---- staging descriptors: up to 3 tasks/thread, hoisted ----
  // task: load float4 pair (2 channels x 4 px), pack f16x2 (k-pair), write
  // 4 strided b32 into the k-major LDS tile.
  const float* sptr[3];
  int  soff[3];
  bool svalid[3];
#pragma unroll
  for (int s = 0; s < 3; ++s) {
    const int t = tid + s * NT;
    bool v = t < NTASK;
    const float* p = in1;
    int off = 0;
    if (v) {
      if (t < NT1) {                   // in1: kp(8) x quad(16)
        const int kp = t & 7, qi = t >> 3;
        p   = in1 + gbase + (size_t)(2 * kp) * HW + y * Wn + X0 + 4 * qi;
        off = IN1E + (4 * qi) * KS + 2 * kp;
      } else {                         // in2: ri(9) x kp(8) x quad(20)
        const int t2 = t - NT1;
        const int ri = t2 / 160, rem = t2 - ri * 160;
        const int kp = rem & 7, qi = rem >> 3;
        const int xp = XP0 + 4 * qi;   // global x' of quad start
        const int r  = y + ri - 4;
        v = (unsigned)r < (unsigned)Hn && (unsigned)xp <= (unsigned)(Wn - 4);
        p   = in2 + gbase + (size_t)(2 * kp) * HW +
              (size_t)(v ? r : 0) * Wn + (v ? xp : 0);
        off = IN2E + ri * ROWE + (4 * qi) * KS + 2 * kp;
      }
    }
    sptr[s] = p; soff[s] = off; svalid[s] = v;
  }

  // ---- pre-zero all of LDS once (halo cols / OOB rows stay 0 forever) ----
  for (int i = tid; i < TOTE / 8; i += NT)
    *(uint4*)&sm[i * 8] = uint4{0, 0, 0, 0};

  // per-lane fragment read bases (constant across chunks)
  const int fragoff = n * KS + 4 * g;  // elems: px-col n, k = 4g..4g+3
  const __fp16* ldsA = &sm[IN1E + fragoff];
  const __fp16* ldsB = &sm[IN2E + dy * ROWE + fragoff];

  f32x4 acc[4][2];
#pragma unroll
  for (int w = 0; w < 4; ++w) {
    acc[w][0] = f32x4{0.f, 0.f, 0.f, 0.f};
    acc[w][1] = f32x4{0.f, 0.f, 0.f, 0.f};
  }

  __syncthreads();                     // pre-zero visible

  for (int c = 0; c < NCH; ++c) {
    // ---- stage chunk c ----
#pragma unroll
    for (int s = 0; s < 3; ++s) {
      if (svalid[s]) {
        const float* p = sptr[s] + (size_t)c * KC * HW;
        const float4 f0 = *(const float4*)p;
        const float4 f1 = *(const float4*)(p + HW);
        const int o = soff[s];
        *(unsigned*)&sm[o         ] = packh2(f0.x, f1.x);
        *(unsigned*)&sm[o +     KS] = packh2(f0.y, f1.y);
        *(unsigned*)&sm[o + 2 * KS] = packh2(f0.z, f1.z);
        *(unsigned*)&sm[o + 3 * KS] = packh2(f0.w, f1.w);
      }
    }
    __syncthreads();

    // ---- compute: 9 ds_read_b64 + 8 mfma ----
    half4 Bf[5];
#pragma unroll
    for (int sw = 0; sw < 5; ++sw)
      Bf[sw] = *(const half4*)&ldsB[sw * 16 * KS];
#pragma unroll
    for (int w = 0; w < 4; ++w) {
      const half4 Af = *(const half4*)&ldsA[w * 16 * KS];
      acc[w][0] = mfma16(Af, Bf[w],     acc[w][0]);
      acc[w][1] = mfma16(Af, Bf[w + 1], acc[w][1]);
    }
    __syncthreads();
  }

  // ---- epilogue: predicated dword stores over the valid band ----
  // D[m][nn]: lane holds m = 4g+q (q=0..3), nn = n; dx = 16t + n - m.
  const size_t obase = ((size_t)(b * 81 + dy * 9) * Hn + y) * Wn;
#pragma unroll
  for (int w = 0; w < 4; ++w) {
#pragma unroll
    for (int t = 0; t < 2; ++t) {
#pragma unroll
      for (int q = 0; q < 4; ++q) {
        const int m  = 4 * g + q;
        const int dx = 16 * t + n - m;
        if ((unsigned)dx <= 8u)
          out[obase + (size_t)dx * HW + X0 + 16 * w + m] = acc[w][t][q];
      }
    }
  }
}

extern "C" void kernel_launch(void* const* d_in, const int* in_sizes, int n_in,
                              void* d_out, int out_size, void* d_ws, size_t ws_size,
                              hipStream_t stream) {
  const float* in1 = (const float*)d_in[0];
  const float* in2 = (const float*)d_in[1];
  float* out = (float*)d_out;
  dim3 grid(Bn * Hn * 2);   // 2048 blocks: (batch, y, x-half)
  dim3 block(NT);           // 576 threads = 9 waves (wave = dy)
  hipLaunchKernelGGL(corr_kernel, grid, block, 0, stream, in1, in2, out);
}